// Round 10
// baseline (443.771 us; speedup 1.0000x reference)
//
#include <hip/hip_runtime.h>
#include <math.h>

#define H  64
#define F  32
#define NB 4      // batch columns per block
#define NT 768    // 12 waves: 0-3 L0, 4-7 L1, 8-11 helper (one of each per SIMD)
#define HS 80     // h row stride (shorts): 160B -> 2-way banks max (free)

typedef __attribute__((ext_vector_type(8))) short   s8v;   // 8 bf16 payload
typedef __attribute__((ext_vector_type(8))) __bf16  bf8v;  // MFMA operand type
typedef __attribute__((ext_vector_type(4))) float   f4v;   // MFMA accumulator

__device__ __forceinline__ unsigned short f2bf(float x) {   // weight init only
    unsigned u = __builtin_bit_cast(unsigned, x);
    u += 0x7FFFu + ((u >> 16) & 1u);          // RNE
    return (unsigned short)(u >> 16);
}
// HW packed f32->bf16 RNE convert (1 instr)
__device__ __forceinline__ unsigned cvtpk(float a, float b) {
    unsigned r;
    asm("v_cvt_pk_bf16_f32 %0, %1, %2" : "=v"(r) : "v"(a), "v"(b));
    return r;
}
// D = A*B + C ; A = activations (rows = batch-dup), B = weights (cols = gate rows)
__device__ __forceinline__ f4v mfma_(s8v a, s8v b, f4v c) {
    return __builtin_amdgcn_mfma_f32_16x16x32_bf16(
        __builtin_bit_cast(bf8v, a), __builtin_bit_cast(bf8v, b), c, 0, 0, 0);
}
__device__ __forceinline__ float sig_(float x) {
    return __builtin_amdgcn_rcpf(1.0f + __expf(-x));
}
__device__ __forceinline__ float tanh_(float x) {
    return 1.0f - 2.0f * __builtin_amdgcn_rcpf(1.0f + __expf(2.0f * x));
}
// LDS-flush + raw barrier: does NOT drain vmcnt (x loads stay in flight)
__device__ __forceinline__ void bar_lds() {
    asm volatile("s_waitcnt lgkmcnt(0)" ::: "memory");
    __builtin_amdgcn_s_barrier();
}
// Load an 8-wide B-fragment slice of a weight row, bf16-hi only.
__device__ __forceinline__ s8v load_hi(const float* __restrict__ Wrow, int koff) {
    s8v hi;
    #pragma unroll
    for (int i = 0; i < 8; ++i) hi[i] = (short)f2bf(Wrow[koff + i]);
    return hi;
}
// Build a bf16 A-fragment from 8 in-register floats.
__device__ __forceinline__ s8v xfrag(const float4& a, const float4& b) {
    s8v r; unsigned* ru = (unsigned*)&r;
    ru[0] = cvtpk(a.x, a.y); ru[1] = cvtpk(a.z, a.w);
    ru[2] = cvtpk(b.x, b.y); ru[3] = cvtpk(b.z, b.w);
    return r;
}

__global__ __launch_bounds__(NT, 3)
void lstm_v10(const float* __restrict__ x,     // [B,T,F]
              const float* __restrict__ Wih0,  // [4H,F]
              const float* __restrict__ Whh0,  // [4H,H]
              const float* __restrict__ bih0,
              const float* __restrict__ bhh0,
              const float* __restrict__ Wih1,  // [4H,H]
              const float* __restrict__ Whh1,  // [4H,H]
              const float* __restrict__ bih1,
              const float* __restrict__ bhh1,
              const float* __restrict__ fcw,   // [1,H]
              const float* __restrict__ fcb,   // [1]
              float* __restrict__ out,         // [B]
              int T, int B)
{
    const int tid  = threadIdx.x;
    const int w    = tid >> 6;          // 0..11
    const int wl   = w & 3;             // wave within its role group
    const int grp  = w >> 2;            // 0 = L0, 1 = L1, 2 = helper
    const int lane = tid & 63;
    const int j    = lane & 15;         // MFMA col: unit within wave's 16-unit group
    const int hi4  = lane >> 4;         // k-slice for fragments; batch for pointwise
    const int bm   = j >> 2;            // A-fragment batch row map  pi(m) = m>>2
    const int u    = 16 * wl + j;       // this lane's hidden unit
    const int b0   = blockIdx.x * NB;

    __shared__ alignas(16) unsigned short h0[2][NB][HS];   // bf16 acts
    __shared__ alignas(16) unsigned short h1[2][NB][HS];
    __shared__ float XP[3][4][H][NB];   // bias0 + Wih0@x(t): [slot][gate][unit][batch]
    __shared__ float P1[2][4][H][NB];   // bias1 + Wih1@h0(t): [buf][gate][unit][batch]
    __shared__ float part[4][64];

    for (int i = tid; i < 2 * NB * HS; i += NT) {
        (&h0[0][0][0])[i] = 0;
        (&h1[0][0][0])[i] = 0;
    }

    if (grp == 0) {
        // ========== L0 waves: h0(s) = pointwise(XP(s) + Whh0@h0(s-1)) ==========
        s8v whh[4][2];
        #pragma unroll
        for (int g = 0; g < 4; ++g) {
            const int R = 64 * g + 16 * wl + j;
            whh[g][0] = load_hi(&Whh0[R * H], 8 * hi4);
            whh[g][1] = load_hi(&Whh0[R * H], 32 + 8 * hi4);
        }
        __syncthreads();   // prolog barrier (zeros + XP(0),XP(1) visible)

        float c = 0.f;
        int s0 = 0;        // s % 3
        #pragma unroll 1
        for (int s = 0; s <= T + 1; ++s) {
            const int par = s & 1;
            if (s < T) {
                const s8v hf0 = *(const s8v*)&h0[par ^ 1][bm][8 * hi4];
                const s8v hf1 = *(const s8v*)&h0[par ^ 1][bm][8 * (4 + hi4)];
                float xp[4];
                #pragma unroll
                for (int g = 0; g < 4; ++g) xp[g] = XP[s0][g][u][hi4];
                f4v acc[4];
                __builtin_amdgcn_s_setprio(1);
                #pragma unroll
                for (int g = 0; g < 4; ++g) {
                    f4v av = {xp[g], xp[g], xp[g], xp[g]};
                    av = mfma_(hf0, whh[g][0], av);
                    acc[g] = mfma_(hf1, whh[g][1], av);
                }
                __builtin_amdgcn_s_setprio(0);
                const float gi = sig_(acc[0][0]);
                const float gf = sig_(acc[1][0]);
                const float gg = tanh_(acc[2][0]);
                const float go = sig_(acc[3][0]);
                c = gf * c + gi * gg;
                const float hv = go * tanh_(c);
                h0[par][hi4][u] = (unsigned short)cvtpk(hv, hv);
            }
            s0 = (s0 == 2) ? 0 : s0 + 1;
            bar_lds();
        }
    } else if (grp == 1) {
        // ========== L1 waves (lag 2): h1(t=s-2) = pw(P1(t) + Whh1@h1(t-1)) ==========
        s8v whh[4][2];
        #pragma unroll
        for (int g = 0; g < 4; ++g) {
            const int R = 64 * g + 16 * wl + j;
            whh[g][0] = load_hi(&Whh1[R * H], 8 * hi4);
            whh[g][1] = load_hi(&Whh1[R * H], 32 + 8 * hi4);
        }
        const float fcwr = fcw[u];
        __syncthreads();   // prolog barrier

        float c = 0.f;
        #pragma unroll 1
        for (int s = 0; s <= T + 1; ++s) {
            const int par = s & 1;
            if (s >= 2) {
                // t = s-2: P1(t) in buf par (helper wrote at s-1); h1(t-1) in buf par^1
                const s8v hf0 = *(const s8v*)&h1[par ^ 1][bm][8 * hi4];
                const s8v hf1 = *(const s8v*)&h1[par ^ 1][bm][8 * (4 + hi4)];
                float p[4];
                #pragma unroll
                for (int g = 0; g < 4; ++g) p[g] = P1[par][g][u][hi4];
                f4v acc[4];
                __builtin_amdgcn_s_setprio(1);
                #pragma unroll
                for (int g = 0; g < 4; ++g) {
                    f4v av = {p[g], p[g], p[g], p[g]};
                    av = mfma_(hf0, whh[g][0], av);
                    acc[g] = mfma_(hf1, whh[g][1], av);
                }
                __builtin_amdgcn_s_setprio(0);
                const float gi = sig_(acc[0][0]);
                const float gf = sig_(acc[1][0]);
                const float gg = tanh_(acc[2][0]);
                const float go = sig_(acc[3][0]);
                c = gf * c + gi * gg;
                const float hv = go * tanh_(c);
                if (s <= T) {
                    h1[par][hi4][u] = (unsigned short)cvtpk(hv, hv);
                } else {
                    part[wl][lane] = hv * fcwr;   // t = T-1: fc-head partial
                }
            }
            bar_lds();
        }
    } else {
        // ========== helper waves: XP(s+2) and P1(s-1), off the critical chain ==========
        s8v wx[4], wg1[4][2];
        float b0g[4], b1g[4];
        #pragma unroll
        for (int g = 0; g < 4; ++g) {
            const int R = 64 * g + 16 * wl + j;
            wx[g] = load_hi(&Wih0[R * F], 8 * hi4);
            wg1[g][0] = load_hi(&Wih1[R * H], 8 * hi4);
            wg1[g][1] = load_hi(&Wih1[R * H], 32 + 8 * hi4);
            b0g[g] = bih0[R] + bhh0[R];
            b1g[g] = bih1[R] + bhh1[R];
        }
        const float* xrow = x + ((size_t)(b0 + bm) * T) * F + 8 * hi4;
        const int tmax = T - 1;
        // prologue: XP(0), XP(1); prime distance-2 x pipeline with x(2), x(3)
        {
            const float4 p00 = *(const float4*)(xrow);
            const float4 p01 = *(const float4*)(xrow + 4);
            const size_t o1 = (size_t)((1 < tmax) ? 1 : tmax) * F;
            const float4 p10 = *(const float4*)(xrow + o1);
            const float4 p11 = *(const float4*)(xrow + o1 + 4);
            const s8v xf0 = xfrag(p00, p01);
            const s8v xf1 = xfrag(p10, p11);
            #pragma unroll
            for (int g = 0; g < 4; ++g) {
                f4v av = {b0g[g], b0g[g], b0g[g], b0g[g]};
                f4v a = mfma_(xf0, wx[g], av);
                XP[0][g][u][hi4] = a[0];
                f4v bv = {b0g[g], b0g[g], b0g[g], b0g[g]};
                f4v b = mfma_(xf1, wx[g], bv);
                XP[1][g][u][hi4] = b[0];
            }
        }
        const size_t o2 = (size_t)((2 < tmax) ? 2 : tmax) * F;
        const size_t o3 = (size_t)((3 < tmax) ? 3 : tmax) * F;
        float4 xA0 = *(const float4*)(xrow + o2), xA1 = *(const float4*)(xrow + o2 + 4);
        float4 xB0 = *(const float4*)(xrow + o3), xB1 = *(const float4*)(xrow + o3 + 4);
        __syncthreads();   // prolog barrier

        int slot2 = 2;     // (s+2) % 3
        #pragma unroll 1
        for (int s = 0; s <= T + 1; ++s) {
            const int par = s & 1;
            // P1(s-1) = bias1 + Wih1 @ h0(s-1)  (consumed by L1 at step s+1)
            if (s >= 1 && s <= T) {
                const s8v hf0 = *(const s8v*)&h0[par ^ 1][bm][8 * hi4];
                const s8v hf1 = *(const s8v*)&h0[par ^ 1][bm][8 * (4 + hi4)];
                #pragma unroll
                for (int g = 0; g < 4; ++g) {
                    f4v av = {b1g[g], b1g[g], b1g[g], b1g[g]};
                    av = mfma_(hf0, wg1[g][0], av);
                    f4v a = mfma_(hf1, wg1[g][1], av);
                    P1[par ^ 1][g][u][hi4] = a[0];
                }
            }
            // XP(s+2) from in-flight x regs (consumed by L0 at step s+2)
            if (s + 2 < T) {
                float4& r0 = (s & 1) ? xB0 : xA0;
                float4& r1 = (s & 1) ? xB1 : xA1;
                const s8v xf = xfrag(r0, r1);
                #pragma unroll
                for (int g = 0; g < 4; ++g) {
                    f4v av = {b0g[g], b0g[g], b0g[g], b0g[g]};
                    f4v a = mfma_(xf, wx[g], av);
                    XP[slot2][g][u][hi4] = a[0];
                }
                const size_t tld = (size_t)((s + 4 < tmax) ? (s + 4) : tmax) * F;
                r0 = *(const float4*)(xrow + tld);
                r1 = *(const float4*)(xrow + tld + 4);
            }
            slot2 = (slot2 == 2) ? 0 : slot2 + 1;
            bar_lds();
        }
    }

    __syncthreads();   // part[] visible

    // ---- fc head: out[b] = sum_u h1(T-1)[b][u]*fcw[u] + fcb ----
    if (tid < 64) {
        float v = part[0][lane] + part[1][lane] + part[2][lane] + part[3][lane];
        v += __shfl_xor(v, 1);
        v += __shfl_xor(v, 2);
        v += __shfl_xor(v, 4);
        v += __shfl_xor(v, 8);
        if (j == 0) out[b0 + hi4] = v + fcb[0];
    }
}

extern "C" void kernel_launch(void* const* d_in, const int* in_sizes, int n_in,
                              void* d_out, int out_size, void* d_ws, size_t ws_size,
                              hipStream_t stream) {
    const float* x    = (const float*)d_in[0];
    const float* Wih0 = (const float*)d_in[1];
    const float* Whh0 = (const float*)d_in[2];
    const float* bih0 = (const float*)d_in[3];
    const float* bhh0 = (const float*)d_in[4];
    const float* Wih1 = (const float*)d_in[5];
    const float* Whh1 = (const float*)d_in[6];
    const float* bih1 = (const float*)d_in[7];
    const float* bhh1 = (const float*)d_in[8];
    const float* fcw  = (const float*)d_in[9];
    const float* fcb  = (const float*)d_in[10];
    float* out = (float*)d_out;

    const int B = out_size;                 // 1024
    const int T = in_sizes[0] / (B * F);    // 512

    dim3 grid(B / NB), block(NT);
    hipLaunchKernelGGL(lstm_v10, grid, block, 0, stream,
                       x, Wih0, Whh0, bih0, bhh0,
                       Wih1, Whh1, bih1, bhh1, fcw, fcb,
                       out, T, B);
}

// Round 11
// 288.518 us; speedup vs baseline: 1.5381x; 1.5381x over previous
//
#include <hip/hip_runtime.h>
#include <math.h>

#define H  64
#define F  32
#define NB 4      // batch columns per block
#define NT 768    // 12 waves: 0-3 L0, 4-7 L1, 8-11 helper (one of each per SIMD)
#define HS 80     // h row stride (shorts): 160B -> 2-way banks max (free)

typedef __attribute__((ext_vector_type(8))) short   s8v;   // 8 bf16 payload
typedef __attribute__((ext_vector_type(8))) __bf16  bf8v;  // MFMA operand type
typedef __attribute__((ext_vector_type(4))) float   f4v;   // MFMA accumulator

__device__ __forceinline__ unsigned short f2bf(float x) {   // weight init only
    unsigned u = __builtin_bit_cast(unsigned, x);
    u += 0x7FFFu + ((u >> 16) & 1u);          // RNE
    return (unsigned short)(u >> 16);
}
// HW packed f32->bf16 RNE convert (1 instr)
__device__ __forceinline__ unsigned cvtpk(float a, float b) {
    unsigned r;
    asm("v_cvt_pk_bf16_f32 %0, %1, %2" : "=v"(r) : "v"(a), "v"(b));
    return r;
}
// D = A*B + C ; A = activations (rows = batch-dup), B = weights (cols = gate rows)
__device__ __forceinline__ f4v mfma_(s8v a, s8v b, f4v c) {
    return __builtin_amdgcn_mfma_f32_16x16x32_bf16(
        __builtin_bit_cast(bf8v, a), __builtin_bit_cast(bf8v, b), c, 0, 0, 0);
}
__device__ __forceinline__ float sig_(float x) {
    return __builtin_amdgcn_rcpf(1.0f + __expf(-x));
}
__device__ __forceinline__ float tanh_(float x) {
    return 1.0f - 2.0f * __builtin_amdgcn_rcpf(1.0f + __expf(2.0f * x));
}
// LDS-flush + raw barrier: does NOT drain vmcnt (x loads stay in flight)
__device__ __forceinline__ void bar_lds() {
    asm volatile("s_waitcnt lgkmcnt(0)" ::: "memory");
    __builtin_amdgcn_s_barrier();
}
// Load an 8-wide B-fragment slice of a weight row, bf16-hi only.
__device__ __forceinline__ s8v load_hi(const float* __restrict__ Wrow, int koff) {
    s8v hi;
    #pragma unroll
    for (int i = 0; i < 8; ++i) hi[i] = (short)f2bf(Wrow[koff + i]);
    return hi;
}
// Build a bf16 A-fragment from 8 in-register floats.
__device__ __forceinline__ s8v xfrag(const float4& a, const float4& b) {
    s8v r; unsigned* ru = (unsigned*)&r;
    ru[0] = cvtpk(a.x, a.y); ru[1] = cvtpk(a.z, a.w);
    ru[2] = cvtpk(b.x, b.y); ru[3] = cvtpk(b.z, b.w);
    return r;
}

__global__ __launch_bounds__(NT, 3)
void lstm_v11(const float* __restrict__ x,     // [B,T,F]
              const float* __restrict__ Wih0,  // [4H,F]
              const float* __restrict__ Whh0,  // [4H,H]
              const float* __restrict__ bih0,
              const float* __restrict__ bhh0,
              const float* __restrict__ Wih1,  // [4H,H]
              const float* __restrict__ Whh1,  // [4H,H]
              const float* __restrict__ bih1,
              const float* __restrict__ bhh1,
              const float* __restrict__ fcw,   // [1,H]
              const float* __restrict__ fcb,   // [1]
              float* __restrict__ out,         // [B]
              int T, int B)
{
    const int tid  = threadIdx.x;
    const int w    = tid >> 6;          // 0..11
    const int wl   = w & 3;             // wave within its role group
    const int grp  = w >> 2;            // 0 = L0, 1 = L1, 2 = helper
    const int lane = tid & 63;
    const int j    = lane & 15;         // MFMA col: unit within wave's 16-unit group
    const int hi4  = lane >> 4;         // k-slice for fragments; batch for pointwise
    const int bm   = j >> 2;            // A-fragment batch row map  pi(m) = m>>2
    const int u    = 16 * wl + j;       // this lane's hidden unit
    const int b0   = blockIdx.x * NB;

    __shared__ alignas(16) unsigned short h0[2][NB][HS];   // bf16 acts
    __shared__ alignas(16) unsigned short h1[2][NB][HS];
    __shared__ float XP[3][4][H][NB];   // bias0 + Wih0@x(t): [slot][gate][unit][batch]
    __shared__ float P1[2][4][H][NB];   // bias1 + Wih1@h0(t): [buf][gate][unit][batch]
    __shared__ float part[4][64];

    for (int i = tid; i < 2 * NB * HS; i += NT) {
        (&h0[0][0][0])[i] = 0;
        (&h1[0][0][0])[i] = 0;
    }

    if (grp == 0) {
        // ========== L0 waves: h0(s) = pointwise(XP(s) + Whh0@h0(s-1)) ==========
        s8v whh[4][2];
        #pragma unroll
        for (int g = 0; g < 4; ++g) {
            const int R = 64 * g + 16 * wl + j;
            whh[g][0] = load_hi(&Whh0[R * H], 8 * hi4);
            whh[g][1] = load_hi(&Whh0[R * H], 32 + 8 * hi4);
        }
        __syncthreads();   // prolog barrier (zeros + XP(0),XP(1) visible)

        float c = 0.f;
        int s0 = 0;        // s % 3
        #pragma unroll 1
        for (int s = 0; s <= T + 1; ++s) {
            const int par = s & 1;
            if (s < T) {
                const s8v hf0 = *(const s8v*)&h0[par ^ 1][bm][8 * hi4];
                const s8v hf1 = *(const s8v*)&h0[par ^ 1][bm][8 * (4 + hi4)];
                float xp[4];
                #pragma unroll
                for (int g = 0; g < 4; ++g) xp[g] = XP[s0][g][u][hi4];
                f4v acc[4];
                __builtin_amdgcn_s_setprio(1);
                #pragma unroll
                for (int g = 0; g < 4; ++g) {
                    f4v av = {xp[g], xp[g], xp[g], xp[g]};
                    av = mfma_(hf0, whh[g][0], av);
                    acc[g] = mfma_(hf1, whh[g][1], av);
                }
                __builtin_amdgcn_s_setprio(0);
                const float gi = sig_(acc[0][0]);
                const float gf = sig_(acc[1][0]);
                const float gg = tanh_(acc[2][0]);
                const float go = sig_(acc[3][0]);
                c = gf * c + gi * gg;
                const float hv = go * tanh_(c);
                h0[par][hi4][u] = (unsigned short)cvtpk(hv, hv);
            }
            s0 = (s0 == 2) ? 0 : s0 + 1;
            bar_lds();
        }
    } else if (grp == 1) {
        // ========== L1 waves (lag 2): h1(t=s-2) = pw(P1(t) + Whh1@h1(t-1)) ==========
        s8v whh[4][2];
        #pragma unroll
        for (int g = 0; g < 4; ++g) {
            const int R = 64 * g + 16 * wl + j;
            whh[g][0] = load_hi(&Whh1[R * H], 8 * hi4);
            whh[g][1] = load_hi(&Whh1[R * H], 32 + 8 * hi4);
        }
        const float fcwr = fcw[u];
        __syncthreads();   // prolog barrier

        float c = 0.f;
        #pragma unroll 1
        for (int s = 0; s <= T + 1; ++s) {
            const int par = s & 1;
            if (s >= 2) {
                // t = s-2: P1(t) in buf par (helper wrote at s-1); h1(t-1) in buf par^1
                const s8v hf0 = *(const s8v*)&h1[par ^ 1][bm][8 * hi4];
                const s8v hf1 = *(const s8v*)&h1[par ^ 1][bm][8 * (4 + hi4)];
                float p[4];
                #pragma unroll
                for (int g = 0; g < 4; ++g) p[g] = P1[par][g][u][hi4];
                f4v acc[4];
                __builtin_amdgcn_s_setprio(1);
                #pragma unroll
                for (int g = 0; g < 4; ++g) {
                    f4v av = {p[g], p[g], p[g], p[g]};
                    av = mfma_(hf0, whh[g][0], av);
                    acc[g] = mfma_(hf1, whh[g][1], av);
                }
                __builtin_amdgcn_s_setprio(0);
                const float gi = sig_(acc[0][0]);
                const float gf = sig_(acc[1][0]);
                const float gg = tanh_(acc[2][0]);
                const float go = sig_(acc[3][0]);
                c = gf * c + gi * gg;
                const float hv = go * tanh_(c);
                if (s <= T) {
                    h1[par][hi4][u] = (unsigned short)cvtpk(hv, hv);
                } else {
                    part[wl][lane] = hv * fcwr;   // t = T-1: fc-head partial
                }
            }
            bar_lds();
        }
    } else {
        // ========== helper waves: XP(s+2) and P1(s-1), off the critical chain ==========
        s8v wx[4], wg1[4][2];
        float b0g[4], b1g[4];
        #pragma unroll
        for (int g = 0; g < 4; ++g) {
            const int R = 64 * g + 16 * wl + j;
            wx[g] = load_hi(&Wih0[R * F], 8 * hi4);
            wg1[g][0] = load_hi(&Wih1[R * H], 8 * hi4);
            wg1[g][1] = load_hi(&Wih1[R * H], 32 + 8 * hi4);
            b0g[g] = bih0[R] + bhh0[R];
            b1g[g] = bih1[R] + bhh1[R];
        }
        const float* xrow = x + ((size_t)(b0 + bm) * T) * F + 8 * hi4;
        const int tmax = T - 1;
        // prologue: XP(0), XP(1); prime distance-2 x pipeline with x(2), x(3)
        {
            const float4 p00 = *(const float4*)(xrow);
            const float4 p01 = *(const float4*)(xrow + 4);
            const size_t o1 = (size_t)((1 < tmax) ? 1 : tmax) * F;
            const float4 p10 = *(const float4*)(xrow + o1);
            const float4 p11 = *(const float4*)(xrow + o1 + 4);
            const s8v xf0 = xfrag(p00, p01);
            const s8v xf1 = xfrag(p10, p11);
            #pragma unroll
            for (int g = 0; g < 4; ++g) {
                f4v av = {b0g[g], b0g[g], b0g[g], b0g[g]};
                f4v a = mfma_(xf0, wx[g], av);
                XP[0][g][u][hi4] = a[0];
                f4v bv = {b0g[g], b0g[g], b0g[g], b0g[g]};
                f4v b = mfma_(xf1, wx[g], bv);
                XP[1][g][u][hi4] = b[0];
            }
        }
        const size_t o2 = (size_t)((2 < tmax) ? 2 : tmax) * F;
        const size_t o3 = (size_t)((3 < tmax) ? 3 : tmax) * F;
        float4 xA0 = *(const float4*)(xrow + o2), xA1 = *(const float4*)(xrow + o2 + 4);
        float4 xB0 = *(const float4*)(xrow + o3), xB1 = *(const float4*)(xrow + o3 + 4);
        __syncthreads();   // prolog barrier

        int slot2 = 2;     // (s+2) % 3

        // one helper sub-step; r0/r1 are NAMED regs bound at compile time (no scratch)
        auto hstep = [&](int s, int par, float4& r0, float4& r1) {
            // P1(s-1) = bias1 + Wih1 @ h0(s-1)  (consumed by L1 at step s+1)
            if (s >= 1 && s <= T) {
                const s8v hf0 = *(const s8v*)&h0[par ^ 1][bm][8 * hi4];
                const s8v hf1 = *(const s8v*)&h0[par ^ 1][bm][8 * (4 + hi4)];
                #pragma unroll
                for (int g = 0; g < 4; ++g) {
                    f4v av = {b1g[g], b1g[g], b1g[g], b1g[g]};
                    av = mfma_(hf0, wg1[g][0], av);
                    f4v a = mfma_(hf1, wg1[g][1], av);
                    P1[par ^ 1][g][u][hi4] = a[0];
                }
            }
            // XP(s+2) from in-flight x regs (consumed by L0 at step s+2)
            if (s + 2 < T) {
                const s8v xf = xfrag(r0, r1);
                #pragma unroll
                for (int g = 0; g < 4; ++g) {
                    f4v av = {b0g[g], b0g[g], b0g[g], b0g[g]};
                    f4v a = mfma_(xf, wx[g], av);
                    XP[slot2][g][u][hi4] = a[0];
                }
                const size_t tld = (size_t)((s + 4 < tmax) ? (s + 4) : tmax) * F;
                r0 = *(const float4*)(xrow + tld);
                r1 = *(const float4*)(xrow + tld + 4);
            }
            slot2 = (slot2 == 2) ? 0 : slot2 + 1;
            bar_lds();
        };

        #pragma unroll 1
        for (int s = 0; s < T + 2; s += 2) {   // T even -> covers s = 0 .. T+1
            hstep(s,     0, xA0, xA1);
            hstep(s + 1, 1, xB0, xB1);
        }
    }

    __syncthreads();   // part[] visible

    // ---- fc head: out[b] = sum_u h1(T-1)[b][u]*fcw[u] + fcb ----
    if (tid < 64) {
        float v = part[0][lane] + part[1][lane] + part[2][lane] + part[3][lane];
        v += __shfl_xor(v, 1);
        v += __shfl_xor(v, 2);
        v += __shfl_xor(v, 4);
        v += __shfl_xor(v, 8);
        if (j == 0) out[b0 + hi4] = v + fcb[0];
    }
}

extern "C" void kernel_launch(void* const* d_in, const int* in_sizes, int n_in,
                              void* d_out, int out_size, void* d_ws, size_t ws_size,
                              hipStream_t stream) {
    const float* x    = (const float*)d_in[0];
    const float* Wih0 = (const float*)d_in[1];
    const float* Whh0 = (const float*)d_in[2];
    const float* bih0 = (const float*)d_in[3];
    const float* bhh0 = (const float*)d_in[4];
    const float* Wih1 = (const float*)d_in[5];
    const float* Whh1 = (const float*)d_in[6];
    const float* bih1 = (const float*)d_in[7];
    const float* bhh1 = (const float*)d_in[8];
    const float* fcw  = (const float*)d_in[9];
    const float* fcb  = (const float*)d_in[10];
    float* out = (float*)d_out;

    const int B = out_size;                 // 1024
    const int T = in_sizes[0] / (B * F);    // 512

    dim3 grid(B / NB), block(NT);
    hipLaunchKernelGGL(lstm_v11, grid, block, 0, stream,
                       x, Wih0, Whh0, bih0, bhh0,
                       Wih1, Whh1, bih1, bhh1, fcw, fcb,
                       out, T, B);
}